// Round 1
// baseline (345.209 us; speedup 1.0000x reference)
//
#include <hip/hip_runtime.h>

#define N_SEQ 256
#define T_LEN 1024
#define TP1   (T_LEN + 1)          // 1025
#define J_NUM 24
#define SEQ_ITEMS (TP1 * J_NUM)    // 24600 items per sequence
#define TOTAL_ITEMS (N_SEQ * SEQ_ITEMS)      // 6,297,600
#define GP_TOTAL (N_SEQ * TP1 * J_NUM * 3)   // global_pos element count

#define ITEMS_PT 4
#define SEQ_THREADS (SEQ_ITEMS / ITEMS_PT)    // 6150 threads per sequence
#define TOTAL_THREADS (TOTAL_ITEMS / ITEMS_PT)// 1,574,400
#define NBLOCKS_B (TOTAL_THREADS / 256)       // 6150 blocks

// ---------------------------------------------------------------------------
// Kernel A: per-sequence scans. 1 block per sequence, 1024 threads.
// Writes ws4[n*TP1+t] = (w, y, pos_x, pos_z).  (unchanged)
// ---------------------------------------------------------------------------
__device__ __forceinline__ float block_scan_incl(float v, float* wsum, int tid) {
    const int lane = tid & 63;
    const int wid  = tid >> 6;
    #pragma unroll
    for (int off = 1; off < 64; off <<= 1) {
        float u = __shfl_up(v, off, 64);
        if (lane >= off) v += u;
    }
    if (lane == 63) wsum[wid] = v;
    __syncthreads();
    if (tid == 0) {
        float acc = 0.0f;
        #pragma unroll
        for (int i = 0; i < 16; ++i) { float t = wsum[i]; wsum[i] = acc; acc += t; }
    }
    __syncthreads();
    return v + wsum[wid];
}

extern "C" __global__ void __launch_bounds__(1024)
scan_kernel(const float* __restrict__ root_rvel,   // (N, T, 1, 1)
            const float* __restrict__ root_vel,    // (N, T, 1, 2)
            float4* __restrict__ ws4)              // (N, T+1) (w, y, px, pz)
{
    const int n   = blockIdx.x;
    const int tid = threadIdx.x;

    __shared__ float  r_s[TP1];
    __shared__ float2 quat_s[TP1];
    __shared__ float  ws_a[16], ws_b[16], ws_c[16];

    // scan root_rvel -> cumulative yaw angle
    {
        float v = root_rvel[n * T_LEN + tid];
        float incl = block_scan_incl(v, ws_a, tid);
        if (tid == 0) r_s[0] = 0.0f;
        r_s[tid + 1] = incl;
    }
    __syncthreads();

    // axis-angle (0, r, 0) -> quat (w, y)
    for (int idx = tid; idx < TP1; idx += 1024) {
        float r     = r_s[idx];
        float angle = fabsf(r);
        float half  = 0.5f * angle;
        float k = (angle < 1e-6f) ? (0.5f - angle * angle * (1.0f / 48.0f))
                                  : (__builtin_sinf(half) / angle);
        quat_s[idx] = make_float2(__builtin_cosf(half), r * k);
    }
    __syncthreads();

    // rotate root_vel by quat[t], scan -> displacement (x, z); y is exactly 0
    {
        float2 vel = ((const float2*)root_vel)[n * T_LEN + tid];
        float2 q   = quat_s[tid];
        float  w = q.x, y = q.y;
        float t1x = w * vel.x + y * vel.y;
        float t1z = w * vel.y - y * vel.x;
        float ax  = t1x * w + t1z * y;
        float az  = t1z * w - t1x * y;
        float ix = block_scan_incl(ax, ws_b, tid);
        float iz = block_scan_incl(az, ws_c, tid);
        float2 qn = quat_s[tid + 1];
        ws4[n * TP1 + tid + 1] = make_float4(qn.x, qn.y, ix, iz);
        if (tid == 0) ws4[n * TP1] = make_float4(1.0f, 0.0f, 0.0f, 0.0f);
    }
}

// ---------------------------------------------------------------------------
// Kernel B: 4 items per thread, no LDS, no barriers.
// Alignment facts that make this work:
//   - 4 items = 24 rot floats = 6 aligned float4   (per-thread rot loads)
//   - 4 items = 12 pos floats = 3 aligned float4
//   - 4 items = 16 out_rot floats = 4 aligned float4
//   - 4 items = 12 out_pos floats = 3 aligned float4
//   - 24 % 4 == 0 and SEQ_ITEMS % 4 == 0  ->  the 4 items of one thread
//     always share the same (seq, t)  ->  ONE ws4 load per thread.
// Each thread issues 10 independent float4 loads up front (ILP for latency
// hiding), does 4 independent quat conversions in registers, stores 7 float4.
// ---------------------------------------------------------------------------
extern "C" __global__ void __launch_bounds__(256)
elem_kernel(const float4* __restrict__ rot4,      // local_rot as float4
            const float4* __restrict__ pos4,      // local_pos as float4
            const float4* __restrict__ ws4,       // (N, T+1)
            float4* __restrict__ out_rot4,        // out_rot as float4
            float4* __restrict__ out_pos4)        // out_pos as float4
{
    const unsigned g = blockIdx.x * 256u + (unsigned)threadIdx.x;

    // (seq, t) shared by all 4 items of this thread
    const unsigned seq = g / (unsigned)SEQ_THREADS;          // /6150
    const unsigned rem = g - seq * (unsigned)SEQ_THREADS;
    const unsigned t   = rem / 6u;                           // 6 threads per (seq,t)

    const float4 wq = ws4[seq * (unsigned)TP1 + t];
    const float w = wq.x, yq = wq.y;

    // ---- issue all loads up front ----
    union { float4 v[6]; float f[24]; } R;
    const float4* rb = rot4 + (size_t)g * 6;
    #pragma unroll
    for (int k = 0; k < 6; ++k) R.v[k] = rb[k];

    union { float4 v[3]; float f[12]; } P;
    const float4* pb = pos4 + (size_t)g * 3;
    #pragma unroll
    for (int k = 0; k < 3; ++k) P.v[k] = pb[k];

    union { float4 v[3]; float f[12]; } OP;

    float4* ob = out_rot4 + (size_t)g * 4;

    #pragma unroll
    for (int i = 0; i < ITEMS_PT; ++i) {
        // ---- 6d -> rotation matrix -> quat ----
        float a1x = R.f[6*i+0], a1y = R.f[6*i+1], a1z = R.f[6*i+2];
        float a2x = R.f[6*i+3], a2y = R.f[6*i+4], a2z = R.f[6*i+5];

        float inv1 = __builtin_amdgcn_rsqf(a1x * a1x + a1y * a1y + a1z * a1z);
        float b1x = a1x * inv1, b1y = a1y * inv1, b1z = a1z * inv1;
        float dp  = b1x * a2x + b1y * a2y + b1z * a2z;
        float px  = a2x - dp * b1x, py = a2y - dp * b1y, pz = a2z - dp * b1z;
        float inv2 = __builtin_amdgcn_rsqf(px * px + py * py + pz * pz);
        float b2x = px * inv2, b2y = py * inv2, b2z = pz * inv2;
        float b3x = b1y * b2z - b1z * b2y;
        float b3y = b1z * b2x - b1x * b2z;
        float b3z = b1x * b2y - b1y * b2x;

        float m00 = b1x, m01 = b1y, m02 = b1z;
        float m10 = b2x, m11 = b2y, m12 = b2z;
        float m20 = b3x, m21 = b3y, m22 = b3z;

        // squared q_abs (relu'd); argmax on squares == argmax on q_abs
        float s0 = fmaxf(1.0f + m00 + m11 + m22, 0.0f);
        float s1 = fmaxf(1.0f + m00 - m11 - m22, 0.0f);
        float s2 = fmaxf(1.0f - m00 + m11 - m22, 0.0f);
        float s3 = fmaxf(1.0f - m00 - m11 + m22, 0.0f);

        int best = 0; float bs = s0;
        if (s1 > bs) { best = 1; bs = s1; }
        if (s2 > bs) { best = 2; bs = s2; }
        if (s3 > bs) { best = 3; bs = s3; }

        float lw, lx, ly, lz;
        if (best == 0)      { lw = bs;         lx = m21 - m12;  ly = m02 - m20;  lz = m10 - m01; }
        else if (best == 1) { lw = m21 - m12;  lx = bs;         ly = m10 + m01;  lz = m02 + m20; }
        else if (best == 2) { lw = m02 - m20;  lx = m10 + m01;  ly = bs;         lz = m21 + m12; }
        else                { lw = m10 - m01;  lx = m20 + m02;  ly = m21 + m12;  lz = bs;        }

        float bv   = __builtin_amdgcn_sqrtf(bs);
        float invd = __builtin_amdgcn_rcpf(2.0f * fmaxf(bv, 0.1f));
        lw *= invd; lx *= invd; ly *= invd; lz *= invd;

        // compose with yaw quat (w, 0, y, 0), standardize
        float ow = w * lw - yq * ly;
        float ox = w * lx + yq * lz;
        float oy = w * ly + yq * lw;
        float oz = w * lz - yq * lx;
        if (ow < 0.0f) { ow = -ow; ox = -ox; oy = -oy; oz = -oz; }
        ob[i] = make_float4(ow, ox, oy, oz);   // 1 aligned float4 per item

        // ---- rotate local_pos, add root displacement ----
        float vx = P.f[3*i+0], vy = P.f[3*i+1], vz = P.f[3*i+2];
        float t1x = w * vx + yq * vz;
        float t1z = w * vz - yq * vx;
        OP.f[3*i+0] = t1x * w + t1z * yq + wq.z;
        OP.f[3*i+1] = (w * w + yq * yq) * vy;
        OP.f[3*i+2] = t1z * w - t1x * yq + wq.w;
    }

    // ---- drain out_pos: 3 aligned float4 per thread ----
    float4* opb = out_pos4 + (size_t)g * 3;
    #pragma unroll
    for (int k = 0; k < 3; ++k) opb[k] = OP.v[k];
}

extern "C" void kernel_launch(void* const* d_in, const int* in_sizes, int n_in,
                              void* d_out, int out_size, void* d_ws, size_t ws_size,
                              hipStream_t stream) {
    (void)in_sizes; (void)n_in; (void)ws_size; (void)out_size;
    const float* root_rvel = (const float*)d_in[0];
    const float* local_pos = (const float*)d_in[1];
    const float* local_rot = (const float*)d_in[2];
    const float* root_vel  = (const float*)d_in[3];
    float* out = (float*)d_out;

    float4* ws4 = (float4*)d_ws;   // N*TP1 float4 = 4.2 MB

    scan_kernel<<<N_SEQ, 1024, 0, stream>>>(root_rvel, root_vel, ws4);

    elem_kernel<<<NBLOCKS_B, 256, 0, stream>>>(
        (const float4*)local_rot, (const float4*)local_pos, ws4,
        (float4*)(out + GP_TOTAL),   // out_rot
        (float4*)out);               // out_pos
}

// Round 2
// 340.632 us; speedup vs baseline: 1.0134x; 1.0134x over previous
//
#include <hip/hip_runtime.h>

#define N_SEQ 256
#define T_LEN 1024
#define TP1   (T_LEN + 1)          // 1025
#define J_NUM 24
#define SEQ_ITEMS (TP1 * J_NUM)    // 24600 items per sequence
#define TOTAL_ITEMS (N_SEQ * SEQ_ITEMS)      // 6,297,600
#define GP_TOTAL (N_SEQ * TP1 * J_NUM * 3)   // global_pos element count

#define IPB 512                               // items per block
#define NBLOCKS_B (TOTAL_ITEMS / IPB)         // 12300 blocks

// ---------------------------------------------------------------------------
// Kernel A: per-sequence scans. 1 block per sequence, 1024 threads.
// Writes ws4[n*TP1+t] = (w, y, pos_x, pos_z).  (unchanged)
// ---------------------------------------------------------------------------
__device__ __forceinline__ float block_scan_incl(float v, float* wsum, int tid) {
    const int lane = tid & 63;
    const int wid  = tid >> 6;
    #pragma unroll
    for (int off = 1; off < 64; off <<= 1) {
        float u = __shfl_up(v, off, 64);
        if (lane >= off) v += u;
    }
    if (lane == 63) wsum[wid] = v;
    __syncthreads();
    if (tid == 0) {
        float acc = 0.0f;
        #pragma unroll
        for (int i = 0; i < 16; ++i) { float t = wsum[i]; wsum[i] = acc; acc += t; }
    }
    __syncthreads();
    return v + wsum[wid];
}

extern "C" __global__ void __launch_bounds__(1024)
scan_kernel(const float* __restrict__ root_rvel,   // (N, T, 1, 1)
            const float* __restrict__ root_vel,    // (N, T, 1, 2)
            float4* __restrict__ ws4)              // (N, T+1) (w, y, px, pz)
{
    const int n   = blockIdx.x;
    const int tid = threadIdx.x;

    __shared__ float  r_s[TP1];
    __shared__ float2 quat_s[TP1];
    __shared__ float  ws_a[16], ws_b[16], ws_c[16];

    // scan root_rvel -> cumulative yaw angle
    {
        float v = root_rvel[n * T_LEN + tid];
        float incl = block_scan_incl(v, ws_a, tid);
        if (tid == 0) r_s[0] = 0.0f;
        r_s[tid + 1] = incl;
    }
    __syncthreads();

    // axis-angle (0, r, 0) -> quat (w, y)
    for (int idx = tid; idx < TP1; idx += 1024) {
        float r     = r_s[idx];
        float angle = fabsf(r);
        float half  = 0.5f * angle;
        float k = (angle < 1e-6f) ? (0.5f - angle * angle * (1.0f / 48.0f))
                                  : (__builtin_sinf(half) / angle);
        quat_s[idx] = make_float2(__builtin_cosf(half), r * k);
    }
    __syncthreads();

    // rotate root_vel by quat[t], scan -> displacement (x, z); y is exactly 0
    {
        float2 vel = ((const float2*)root_vel)[n * T_LEN + tid];
        float2 q   = quat_s[tid];
        float  w = q.x, y = q.y;
        float t1x = w * vel.x + y * vel.y;
        float t1z = w * vel.y - y * vel.x;
        float ax  = t1x * w + t1z * y;
        float az  = t1z * w - t1x * y;
        float ix = block_scan_incl(ax, ws_b, tid);
        float iz = block_scan_incl(az, ws_c, tid);
        float2 qn = quat_s[tid + 1];
        ws4[n * TP1 + tid + 1] = make_float4(qn.x, qn.y, ix, iz);
        if (tid == 0) ws4[n * TP1] = make_float4(1.0f, 0.0f, 0.0f, 0.0f);
    }
}

// ---------------------------------------------------------------------------
// Per-item compute: 6d rot -> quat, compose with yaw; rotate pos + displace.
// bs is always >= 1 (s0+s1+s2+s3 == 4), so the relu and the 0.1 floor of the
// reference are no-ops on the selected branch and are dropped.
// ---------------------------------------------------------------------------
__device__ __forceinline__ void process_item(
    float a1x, float a1y, float a1z, float a2x, float a2y, float a2z,
    float vx,  float vy,  float vz,  float4 wq,
    float4* __restrict__ out_rot_addr, float* __restrict__ s_out3)
{
    const float w = wq.x, yq = wq.y;

    float inv1 = __builtin_amdgcn_rsqf(a1x * a1x + a1y * a1y + a1z * a1z);
    float b1x = a1x * inv1, b1y = a1y * inv1, b1z = a1z * inv1;
    float dp  = b1x * a2x + b1y * a2y + b1z * a2z;
    float px  = a2x - dp * b1x, py = a2y - dp * b1y, pz = a2z - dp * b1z;
    float inv2 = __builtin_amdgcn_rsqf(px * px + py * py + pz * pz);
    float b2x = px * inv2, b2y = py * inv2, b2z = pz * inv2;
    float b3x = b1y * b2z - b1z * b2y;
    float b3y = b1z * b2x - b1x * b2z;
    float b3z = b1x * b2y - b1y * b2x;

    float m00 = b1x, m01 = b1y, m02 = b1z;
    float m10 = b2x, m11 = b2y, m12 = b2z;
    float m20 = b3x, m21 = b3y, m22 = b3z;

    float s0 = 1.0f + m00 + m11 + m22;
    float s1 = 1.0f + m00 - m11 - m22;
    float s2 = 1.0f - m00 + m11 - m22;
    float s3 = 1.0f - m00 - m11 + m22;

    int best = 0; float bs = s0;
    if (s1 > bs) { best = 1; bs = s1; }
    if (s2 > bs) { best = 2; bs = s2; }
    if (s3 > bs) { best = 3; bs = s3; }

    float c0 = m21 - m12, c1 = m02 - m20, c2 = m10 - m01;
    float d0 = m10 + m01, d1 = m02 + m20, d2 = m21 + m12;

    float lw = best == 0 ? bs : (best == 1 ? c0 : (best == 2 ? c1 : c2));
    float lx = best == 0 ? c0 : (best == 1 ? bs : (best == 2 ? d0 : d1));
    float ly = best == 0 ? c1 : (best == 1 ? d0 : (best == 2 ? bs : d2));
    float lz = best == 0 ? c2 : (best == 1 ? d1 : (best == 2 ? d2 : bs));

    float invd = __builtin_amdgcn_rcpf(2.0f * __builtin_amdgcn_sqrtf(bs));
    lw *= invd; lx *= invd; ly *= invd; lz *= invd;

    // compose with yaw quat (w, 0, y, 0), standardize
    float ow = w * lw - yq * ly;
    float ox = w * lx + yq * lz;
    float oy = w * ly + yq * lw;
    float oz = w * lz - yq * lx;
    if (ow < 0.0f) { ow = -ow; ox = -ox; oy = -oy; oz = -oz; }
    *out_rot_addr = make_float4(ow, ox, oy, oz);     // coalesced float4/item

    // rotate local_pos by yaw, add root displacement
    float t1x = w * vx + yq * vz;
    float t1z = w * vz - yq * vx;
    s_out3[0] = t1x * w + t1z * yq + wq.z;
    s_out3[1] = (w * w + yq * yq) * vy;
    s_out3[2] = t1z * w - t1x * yq + wq.w;
}

// ---------------------------------------------------------------------------
// Kernel B: 512 items per 256-thread block, 2 items per thread.
//   phase 1: coalesced global->LDS staging, LINEAR layout (ds_write_b128,
//            zero address math)
//   phase 2: per-thread strided LDS reads (24B/12B stride; <=4-way conflicts
//            on 3 small reads each -- negligible per m136)
//   phase 3: compute; out_rot stored direct (coalesced float4); out_pos
//            staged into the REUSED rot LDS region
//   phase 4: coalesced drain of out_pos
// LDS = 18 KiB -> 8 blocks/CU; __launch_bounds__(256,8) -> 32 waves/CU.
// ---------------------------------------------------------------------------
extern "C" __global__ void __launch_bounds__(256, 8)
elem_kernel(const float4* __restrict__ rot4,      // local_rot as float4
            const float4* __restrict__ pos4,      // local_pos as float4
            const float4* __restrict__ ws4,       // (N, T+1)
            float4* __restrict__ out_rot4,        // out_rot as float4
            float4* __restrict__ out_pos4)        // out_pos as float4
{
    __shared__ float4 s_rot4[768];   // 12 KiB: 512 items x 6 floats
    __shared__ float4 s_pos4[384];   //  6 KiB: 512 items x 3 floats
    float* s_rot = (float*)s_rot4;
    float* s_pos = (float*)s_pos4;
    // out_pos staging reuses the rot region (all rot reads complete first)
    float*  s_out  = s_rot;
    float4* s_out4 = s_rot4;

    const int tid = threadIdx.x;
    const unsigned blk = blockIdx.x;

    // ---- phase 1: stage, fully coalesced, linear ----
    {
        const float4* rb = rot4 + (size_t)blk * 768;
        s_rot4[tid]       = rb[tid];
        s_rot4[tid + 256] = rb[tid + 256];
        s_rot4[tid + 512] = rb[tid + 512];
        const float4* pb = pos4 + (size_t)blk * 384;
        s_pos4[tid] = pb[tid];
        if (tid < 128) s_pos4[tid + 256] = pb[tid + 256];
    }

    // ---- ws gather for both items (independent of LDS) ----
    const unsigned a0 = blk * (unsigned)IPB + (unsigned)tid;
    const unsigned a1 = a0 + 256u;
    const unsigned seq0 = a0 / (unsigned)SEQ_ITEMS;
    const unsigned t0   = (a0 - seq0 * (unsigned)SEQ_ITEMS) / (unsigned)J_NUM;
    const unsigned seq1 = a1 / (unsigned)SEQ_ITEMS;
    const unsigned t1   = (a1 - seq1 * (unsigned)SEQ_ITEMS) / (unsigned)J_NUM;
    const float4 wq0 = ws4[seq0 * (unsigned)TP1 + t0];
    const float4 wq1 = ws4[seq1 * (unsigned)TP1 + t1];

    __syncthreads();

    // ---- phase 2: read my 2 items into registers ----
    const float2* s_rot2 = (const float2*)s_rot;
    const int L0 = tid, L1 = tid + 256;
    float2 ra0 = s_rot2[3 * L0 + 0];
    float2 rb0 = s_rot2[3 * L0 + 1];
    float2 rc0 = s_rot2[3 * L0 + 2];
    float2 ra1 = s_rot2[3 * L1 + 0];
    float2 rb1 = s_rot2[3 * L1 + 1];
    float2 rc1 = s_rot2[3 * L1 + 2];
    float p0x = s_pos[3 * L0 + 0], p0y = s_pos[3 * L0 + 1], p0z = s_pos[3 * L0 + 2];
    float p1x = s_pos[3 * L1 + 0], p1y = s_pos[3 * L1 + 1], p1z = s_pos[3 * L1 + 2];

    __syncthreads();   // all rot reads done before s_out overwrites the region

    // ---- phase 3: compute + direct out_rot store + out_pos LDS stage ----
    process_item(ra0.x, ra0.y, rb0.x, rb0.y, rc0.x, rc0.y,
                 p0x, p0y, p0z, wq0, &out_rot4[a0], &s_out[3 * L0]);
    process_item(ra1.x, ra1.y, rb1.x, rb1.y, rc1.x, rc1.y,
                 p1x, p1y, p1z, wq1, &out_rot4[a1], &s_out[3 * L1]);

    __syncthreads();

    // ---- phase 4: coalesced drain of out_pos (384 float4 per block) ----
    float4* opb = out_pos4 + (size_t)blk * 384;
    opb[tid] = s_out4[tid];
    if (tid < 128) opb[tid + 256] = s_out4[tid + 256];
}

extern "C" void kernel_launch(void* const* d_in, const int* in_sizes, int n_in,
                              void* d_out, int out_size, void* d_ws, size_t ws_size,
                              hipStream_t stream) {
    (void)in_sizes; (void)n_in; (void)ws_size; (void)out_size;
    const float* root_rvel = (const float*)d_in[0];
    const float* local_pos = (const float*)d_in[1];
    const float* local_rot = (const float*)d_in[2];
    const float* root_vel  = (const float*)d_in[3];
    float* out = (float*)d_out;

    float4* ws4 = (float4*)d_ws;   // N*TP1 float4 = 4.2 MB

    scan_kernel<<<N_SEQ, 1024, 0, stream>>>(root_rvel, root_vel, ws4);

    elem_kernel<<<NBLOCKS_B, 256, 0, stream>>>(
        (const float4*)local_rot, (const float4*)local_pos, ws4,
        (float4*)(out + GP_TOTAL),   // out_rot
        (float4*)out);               // out_pos
}